// Round 4
// baseline (166.196 us; speedup 1.0000x reference)
//
#include <hip/hip_runtime.h>
#include <math.h>

// EfficientGCN preprocess:
//   x: (N=128, C=3, T=300, V=25, M=2) fp32
//   out: (N, 3, 2C=6, T, V, M) fp32
// Branch 0 (joint):   [x ; x - x[:, :, :, 1, :]]
// Branch 1 (velocity):[x[t+1]-x[t] ; x[t+2]-x[t]] for t<T-2 else 0
// Branch 2 (bone):    bv = x - x[parent]; [bv ; acos(bv / (||bv||+1e-4))]
//
// LDS-staged version: block = one (n, 20-frame chunk). Stages 22 frames
// (20 + 2 halo) x 50 floats x 3 channels = 13.2 KB LDS via coalesced float4
// loads. Center / parent / t+1 / t+2 accesses are LDS reads.
// FIX vs round 3: t+2 gather offset is +2 frames = +2*VV*MM floats (=100),
// was written as +2*VV (=50, i.e. t+1) -- the absmax 7.2 failure.

#define NN 128
#define CC 3
#define TT 300
#define VV 25
#define MM 2

typedef float f32x4 __attribute__((ext_vector_type(4)));
typedef float f32x2 __attribute__((ext_vector_type(2)));

constexpr int TVM   = TT * VV * MM;      // 15000 floats per (n,c) plane
constexpr int TV    = TT * VV;           // 7500 float2 sites per plane
constexpr int Q     = TV / 2;            // 3750 float4 per plane
constexpr int OUTP  = 3 * 6 * TVM;       // floats per n in output

constexpr int TBF    = 20;               // frames per block (exact tiling)
constexpr int HALO   = 2;                // +2 frames for velocity lookahead
constexpr int CHUNKS = TT / TBF;         // 15 chunks per n
constexpr int F4PB   = TBF * VV / 2;     // 250 output float4 per block-plane
constexpr int FRF    = VV * MM;          // 50 floats per frame
constexpr int LDS_FL = (TBF + HALO) * FRF;  // 1100 floats per channel

__global__ __launch_bounds__(256)
void egcn_pre_kernel(const float* __restrict__ x,
                     const int* __restrict__ conn,
                     float* __restrict__ out) {
    __shared__ float lds[3 * LDS_FL];    // 13.2 KB
    __shared__ int   connS[VV];

    int bid = blockIdx.x;
    int n   = bid / CHUNKS;
    int blk = bid - n * CHUNKS;
    int tid = threadIdx.x;

    int t0     = blk * TBF;
    int frames = min(TBF + HALO, TT - t0);      // 22 interior, 20 last chunk
    int nf4    = frames * FRF / 4;              // 275 or 250

    const float* xn = x + (size_t)n * CC * TVM;

    if (tid < VV) connS[tid] = conn[tid];
    #pragma unroll
    for (int c = 0; c < 3; ++c) {
        const f32x4* p4 = reinterpret_cast<const f32x4*>(xn + c * TVM + t0 * FRF);
        f32x4* l4 = reinterpret_cast<f32x4*>(lds + c * LDS_FL);
        for (int i = tid; i < nf4; i += 256) l4[i] = p4[i];
    }
    __syncthreads();

    if (tid >= F4PB) return;   // 250 active threads per block

    int sa  = 2 * tid;                // local float2 site A (tl*25 + v)
    int sb  = sa + 1;                 // site B
    int tla = sa / VV, va = sa - tla * VV;
    int tlb = sb / VV, vb = sb - tlb * VV;
    int pa  = connS[va];
    int pb  = connS[vb];
    bool hva = (t0 + tla) < TT - 2;
    bool hvb = (t0 + tlb) < TT - 2;

    // Gather per-channel data from LDS.
    // Halo reads beyond staged frames (last chunk only) stay inside the lds
    // allocation and are select-masked by hva/hvb before use.
    f32x4 xv[3], x2[3];
    f32x2 x1a[3], x1b[3], xca[3], xcb[3], xpa[3], xpb[3];
    #pragma unroll
    for (int c = 0; c < 3; ++c) {
        const float* lc = lds + c * LDS_FL;
        const f32x2* L2 = reinterpret_cast<const f32x2*>(lc);
        xv[c]  = *reinterpret_cast<const f32x4*>(lc + 4 * tid);            // sites sa,sb
        x2[c]  = *reinterpret_cast<const f32x4*>(lc + 4 * tid + 2 * FRF);  // t+2 (=+100 floats)
        x1a[c] = L2[sa + VV];             // t+1 (frame = VV float2)
        x1b[c] = L2[sb + VV];
        xca[c] = L2[tla * VV + 1];        // center joint (broadcast within frame)
        xcb[c] = L2[tlb * VV + 1];
        xpa[c] = L2[tla * VV + pa];       // parent joint
        xpb[c] = L2[tlb * VV + pb];
    }

    // bone vectors + per-(site,m) inverse length
    f32x2 bva[3], bvb[3];
    float sa0 = 0.f, sa1 = 0.f, sb0 = 0.f, sb1 = 0.f;
    #pragma unroll
    for (int c = 0; c < 3; ++c) {
        bva[c].x = xv[c].x - xpa[c].x;
        bva[c].y = xv[c].y - xpa[c].y;
        bvb[c].x = xv[c].z - xpb[c].x;
        bvb[c].y = xv[c].w - xpb[c].y;
        sa0 += bva[c].x * bva[c].x;  sa1 += bva[c].y * bva[c].y;
        sb0 += bvb[c].x * bvb[c].x;  sb1 += bvb[c].y * bvb[c].y;
    }
    float ia0 = 1.0f / (sqrtf(sa0) + 1e-4f);
    float ia1 = 1.0f / (sqrtf(sa1) + 1e-4f);
    float ib0 = 1.0f / (sqrtf(sb0) + 1e-4f);
    float ib1 = 1.0f / (sqrtf(sb1) + 1e-4f);

    int k = blk * F4PB + tid;   // global float4 index within each output plane
    f32x4* o4 = reinterpret_cast<f32x4*>(out + (size_t)n * OUTP);
    #pragma unroll
    for (int c = 0; c < 3; ++c) {
        // branch 0: joint = [x ; x - center]
        __builtin_nontemporal_store(xv[c], &o4[(0 * 6 + c) * Q + k]);
        f32x4 rel;
        rel.x = xv[c].x - xca[c].x;  rel.y = xv[c].y - xca[c].y;
        rel.z = xv[c].z - xcb[c].x;  rel.w = xv[c].w - xcb[c].y;
        __builtin_nontemporal_store(rel, &o4[(0 * 6 + c + 3) * Q + k]);

        // branch 1: velocity = [x(t+1)-x(t) ; x(t+2)-x(t)], zero for t >= T-2
        f32x4 u1, u2;
        u1.x = hva ? x1a[c].x - xv[c].x : 0.f;
        u1.y = hva ? x1a[c].y - xv[c].y : 0.f;
        u1.z = hvb ? x1b[c].x - xv[c].z : 0.f;
        u1.w = hvb ? x1b[c].y - xv[c].w : 0.f;
        u2.x = hva ? x2[c].x - xv[c].x : 0.f;
        u2.y = hva ? x2[c].y - xv[c].y : 0.f;
        u2.z = hvb ? x2[c].z - xv[c].z : 0.f;
        u2.w = hvb ? x2[c].w - xv[c].w : 0.f;
        __builtin_nontemporal_store(u1, &o4[(1 * 6 + c) * Q + k]);
        __builtin_nontemporal_store(u2, &o4[(1 * 6 + c + 3) * Q + k]);

        // branch 2: bone = [bv ; acos(bv * inv_len)]
        f32x4 bn, ang;
        bn.x = bva[c].x;  bn.y = bva[c].y;  bn.z = bvb[c].x;  bn.w = bvb[c].y;
        __builtin_nontemporal_store(bn, &o4[(2 * 6 + c) * Q + k]);
        ang.x = acosf(bva[c].x * ia0);
        ang.y = acosf(bva[c].y * ia1);
        ang.z = acosf(bvb[c].x * ib0);
        ang.w = acosf(bvb[c].y * ib1);
        __builtin_nontemporal_store(ang, &o4[(2 * 6 + c + 3) * Q + k]);
    }
}

extern "C" void kernel_launch(void* const* d_in, const int* in_sizes, int n_in,
                              void* d_out, int out_size, void* d_ws, size_t ws_size,
                              hipStream_t stream) {
    const float* x   = (const float*)d_in[0];
    const int* conn  = (const int*)d_in[1];
    float* out       = (float*)d_out;

    int grid = NN * CHUNKS;   // 128 * 15 = 1920 blocks, 256 threads each
    egcn_pre_kernel<<<grid, 256, 0, stream>>>(x, conn, out);
}